// Round 1
// baseline (11545.128 us; speedup 1.0000x reference)
//
#include <hip/hip_runtime.h>
#include <hip/hip_bf16.h>

#define N_NODES_C 100000
#define N_EDGES_C 500000
#define N_REL_C 6
#define IN_DIM_C 64
#define HID_C 128
#define HEADS_C 4
#define CPH_C 32
#define N_GRAPHS_C 1024

__device__ __forceinline__ void atomAddF(float* p, float v) {
#if defined(__AMDGCN__) || defined(__HIP_DEVICE_COMPILE__)
    unsafeAtomicAdd(p, v);
#else
    atomicAdd(p, v);
#endif
}

// acc[n][c] = sum_r b[r][c]
__global__ __launch_bounds__(256) void init_acc_kernel(float* __restrict__ acc,
                                                       const float* __restrict__ b) {
    int i = blockIdx.x * 256 + threadIdx.x;
    if (i >= N_NODES_C * HID_C) return;
    int c = i & (HID_C - 1);
    float s = 0.f;
#pragma unroll
    for (int r = 0; r < N_REL_C; r++) s += b[r * HID_C + c];
    acc[i] = s;
}

// H[n][c] = sum_k X[n][k] * W[k][c] (+ bias[c] if bias)
// tile: 32 rows x 128 cols per block of 256 threads; thread computes 4x4.
template <int K>
__global__ __launch_bounds__(256) void gemm_nodes(const float* __restrict__ X,
                                                  const float* __restrict__ W,
                                                  const float* __restrict__ bias,
                                                  float* __restrict__ H, int nrows) {
    __shared__ float Wl[64 * HID_C];   // 32KB
    __shared__ float Xl[32 * K];       // 8KB (K=64) / 16KB (K=128)
    const int t = threadIdx.x;
    const int n0 = blockIdx.x * 32;
    const float* Xb = X + (size_t)n0 * K;
    for (int i = t; i < 32 * K / 4; i += 256)
        ((float4*)Xl)[i] = ((const float4*)Xb)[i];

    const int cg = t & 31, rg = t >> 5;
    const int c0 = cg * 4, r0 = rg * 4;
    float acc[4][4];
#pragma unroll
    for (int i = 0; i < 4; i++)
#pragma unroll
        for (int j = 0; j < 4; j++) acc[i][j] = 0.f;

    for (int kb = 0; kb < K; kb += 64) {
        __syncthreads();
        for (int i = t; i < 64 * HID_C / 4; i += 256)
            ((float4*)Wl)[i] = ((const float4*)(W + (size_t)kb * HID_C))[i];
        __syncthreads();
#pragma unroll 4
        for (int k = 0; k < 64; k += 4) {
            float xr[4][4];
#pragma unroll
            for (int i = 0; i < 4; i++) {
                float4 xv = *(const float4*)&Xl[(r0 + i) * K + kb + k];
                xr[i][0] = xv.x; xr[i][1] = xv.y; xr[i][2] = xv.z; xr[i][3] = xv.w;
            }
#pragma unroll
            for (int kk = 0; kk < 4; kk++) {
                float4 wv = *(const float4*)&Wl[(k + kk) * HID_C + c0];
#pragma unroll
                for (int i = 0; i < 4; i++) {
                    acc[i][0] = fmaf(xr[i][kk], wv.x, acc[i][0]);
                    acc[i][1] = fmaf(xr[i][kk], wv.y, acc[i][1]);
                    acc[i][2] = fmaf(xr[i][kk], wv.z, acc[i][2]);
                    acc[i][3] = fmaf(xr[i][kk], wv.w, acc[i][3]);
                }
            }
        }
    }
    float4 bv = make_float4(0.f, 0.f, 0.f, 0.f);
    if (bias) bv = *(const float4*)&bias[c0];
#pragma unroll
    for (int i = 0; i < 4; i++) {
        int row = n0 + r0 + i;
        if (row < nrows) {
            float4 o;
            o.x = acc[i][0] + bv.x; o.y = acc[i][1] + bv.y;
            o.z = acc[i][2] + bv.z; o.w = acc[i][3] + bv.w;
            *(float4*)&H[(size_t)row * HID_C + c0] = o;
        }
    }
}

// al_s[n][h], al_d[n][h] = dot over 32 channels of head h
__global__ __launch_bounds__(256) void attn_logits_kernel(const float* __restrict__ H,
                                                          const float* __restrict__ as_r,
                                                          const float* __restrict__ ad_r,
                                                          float* __restrict__ als,
                                                          float* __restrict__ ald) {
    int i = blockIdx.x * 256 + threadIdx.x;
    if (i >= N_NODES_C * HEADS_C) return;
    int n = i >> 2, h = i & 3;
    const float* hp = H + (size_t)n * HID_C + h * CPH_C;
    const float* ap = as_r + h * CPH_C;
    const float* dp = ad_r + h * CPH_C;
    float ss = 0.f, sd = 0.f;
#pragma unroll
    for (int j = 0; j < CPH_C; j++) {
        float v = hp[j];
        ss = fmaf(v, ap[j], ss);
        sd = fmaf(v, dp[j], sd);
    }
    als[i] = ss;
    ald[i] = sd;
}

// per (edge, head): ex = exp(leaky_relu(al_s[src]+al_d[dst])); den[dst] += ex
__global__ __launch_bounds__(256) void edge_softmax_kernel(const int* __restrict__ ei,
                                                           const float* __restrict__ als,
                                                           const float* __restrict__ ald,
                                                           float* __restrict__ exb,
                                                           float* __restrict__ den) {
    int i = blockIdx.x * 256 + threadIdx.x;
    if (i >= N_EDGES_C * HEADS_C) return;
    int e = i >> 2, h = i & 3;
    int src = ei[e];
    int dst = ei[N_EDGES_C + e];
    float v = als[src * HEADS_C + h] + ald[dst * HEADS_C + h];
    v = v > 0.f ? v : 0.2f * v;
    float xv = expf(v);
    exb[i] = xv;
    atomAddF(&den[dst * HEADS_C + h], xv);
}

// per edge: acc[dst] += h[src] * alpha   (32 lanes/edge, 4 ch each)
__global__ __launch_bounds__(256) void edge_aggregate_kernel(const int* __restrict__ ei,
                                                             const float* __restrict__ Hsrc,
                                                             const float* __restrict__ exb,
                                                             const float* __restrict__ den,
                                                             float* __restrict__ acc) {
    int t = threadIdx.x;
    int e = blockIdx.x * 8 + (t >> 5);
    int lane = t & 31;
    if (e >= N_EDGES_C) return;
    int src = ei[e];
    int dst = ei[N_EDGES_C + e];
    int h = lane >> 3;
    float a = exb[e * HEADS_C + h] / (den[dst * HEADS_C + h] + 1e-16f);
    float4 hv = *(const float4*)(Hsrc + (size_t)src * HID_C + lane * 4);
    float* dp = acc + (size_t)dst * HID_C + lane * 4;
    atomAddF(dp + 0, hv.x * a);
    atomAddF(dp + 1, hv.y * a);
    atomAddF(dp + 2, hv.z * a);
    atomAddF(dp + 3, hv.w * a);
}

// out = layernorm(softsign(in)) * g + be ; one wave per node
__global__ __launch_bounds__(256) void softsign_ln_kernel(const float* __restrict__ in,
                                                          const float* __restrict__ g,
                                                          const float* __restrict__ be,
                                                          float* __restrict__ out) {
    int t = threadIdx.x;
    int n = blockIdx.x * 4 + (t >> 6);
    int lane = t & 63;
    float2 v = *(const float2*)(in + (size_t)n * HID_C + lane * 2);
    float s0 = v.x / (1.f + fabsf(v.x));
    float s1 = v.y / (1.f + fabsf(v.y));
    float sum = s0 + s1, sq = s0 * s0 + s1 * s1;
#pragma unroll
    for (int off = 1; off < 64; off <<= 1) {
        sum += __shfl_xor(sum, off);
        sq += __shfl_xor(sq, off);
    }
    float mu = sum * (1.f / 128.f);
    float var = sq * (1.f / 128.f) - mu * mu;
    float inv = rsqrtf(var + 1e-5f);
    float2 gv = *(const float2*)(g + lane * 2);
    float2 bv = *(const float2*)(be + lane * 2);
    float2 o;
    o.x = (s0 - mu) * inv * gv.x + bv.x;
    o.y = (s1 - mu) * inv * gv.y + bv.y;
    *(float2*)(out + (size_t)n * HID_C + lane * 2) = o;
}

__device__ __forceinline__ int lower_bound_i(const int* __restrict__ a, int n, int v) {
    int lo = 0, hi = n;
    while (lo < hi) {
        int mid = (lo + hi) >> 1;
        if (a[mid] < v) lo = mid + 1; else hi = mid;
    }
    return lo;
}

// one wave (64 threads) per graph; batch is sorted
__global__ void pool_kernel(const float* __restrict__ H, const int* __restrict__ batch,
                            const float* __restrict__ q, float* __restrict__ pooled) {
    int g = blockIdx.x;
    int lane = threadIdx.x;
    int start = lower_bound_i(batch, N_NODES_C, g);
    int end = lower_bound_i(batch, N_NODES_C, g + 1);
    float q0 = q[lane * 2], q1 = q[lane * 2 + 1];
    float p0 = 0.f, p1 = 0.f, den = 0.f;
    for (int n = start; n < end; n++) {
        float2 hv = *(const float2*)(H + (size_t)n * HID_C + lane * 2);
        float part = hv.x * q0 + hv.y * q1;
#pragma unroll
        for (int off = 1; off < 64; off <<= 1) part += __shfl_xor(part, off);
        float exs = expf(part);
        den += exs;
        p0 += exs * hv.x;
        p1 += exs * hv.y;
    }
    float w = 1.f / (den + 1e-16f);
    pooled[(size_t)g * HID_C + lane * 2] = p0 * w;
    pooled[(size_t)g * HID_C + lane * 2 + 1] = p1 * w;
}

extern "C" void kernel_launch(void* const* d_in, const int* in_sizes, int n_in,
                              void* d_out, int out_size, void* d_ws, size_t ws_size,
                              hipStream_t stream) {
    const float* x   = (const float*)d_in[0];
    const int* ei    = (const int*)d_in[1];    // [6,2,E]
    const int* batch = (const int*)d_in[2];
    const float* W1  = (const float*)d_in[3];
    const float* as1 = (const float*)d_in[4];
    const float* ad1 = (const float*)d_in[5];
    const float* b1  = (const float*)d_in[6];
    const float* W2  = (const float*)d_in[7];
    const float* as2 = (const float*)d_in[8];
    const float* ad2 = (const float*)d_in[9];
    const float* b2  = (const float*)d_in[10];
    const float* g1  = (const float*)d_in[11];
    const float* be1 = (const float*)d_in[12];
    const float* g2  = (const float*)d_in[13];
    const float* be2 = (const float*)d_in[14];
    const float* q   = (const float*)d_in[15];
    const float* Wp  = (const float*)d_in[16];
    const float* bp  = (const float*)d_in[17];
    float* out = (float*)d_out;

    float* ws = (float*)d_ws;
    const size_t NH = (size_t)N_NODES_C * HID_C;            // 12.8M floats
    float* A   = ws;                                        // h_r temp [N,128]
    float* B   = ws + NH;                                   // accumulator [N,128]
    float* Cb  = ws + 2 * NH;                               // LN output [N,128]
    float* als = ws + 3 * NH;                               // [N,4]
    float* ald = als + (size_t)N_NODES_C * HEADS_C;
    float* den = ald + (size_t)N_NODES_C * HEADS_C;
    float* exb = den + (size_t)N_NODES_C * HEADS_C;         // [E,4]
    float* pooled = exb + (size_t)N_EDGES_C * HEADS_C;      // [1024,128]

    const int gemm_grid_n = N_NODES_C / 32;                 // 3125
    const int logit_grid = (N_NODES_C * HEADS_C + 255) / 256;
    const int esm_grid = (N_EDGES_C * HEADS_C + 255) / 256;
    const int eagg_grid = N_EDGES_C / 8;                    // 62500
    const int ln_grid = N_NODES_C / 4;                      // 25000

    // ---- layer 1 ----
    init_acc_kernel<<<N_NODES_C * HID_C / 256, 256, 0, stream>>>(B, b1);
    for (int r = 0; r < N_REL_C; r++) {
        gemm_nodes<IN_DIM_C><<<gemm_grid_n, 256, 0, stream>>>(
            x, W1 + (size_t)r * IN_DIM_C * HID_C, nullptr, A, N_NODES_C);
        attn_logits_kernel<<<logit_grid, 256, 0, stream>>>(
            A, as1 + r * HID_C, ad1 + r * HID_C, als, ald);
        hipMemsetAsync(den, 0, (size_t)N_NODES_C * HEADS_C * sizeof(float), stream);
        const int* eir = ei + (size_t)r * 2 * N_EDGES_C;
        edge_softmax_kernel<<<esm_grid, 256, 0, stream>>>(eir, als, ald, exb, den);
        edge_aggregate_kernel<<<eagg_grid, 256, 0, stream>>>(eir, A, exb, den, B);
    }
    softsign_ln_kernel<<<ln_grid, 256, 0, stream>>>(B, g1, be1, Cb);

    // ---- layer 2 ----
    init_acc_kernel<<<N_NODES_C * HID_C / 256, 256, 0, stream>>>(B, b2);
    for (int r = 0; r < N_REL_C; r++) {
        gemm_nodes<HID_C><<<gemm_grid_n, 256, 0, stream>>>(
            Cb, W2 + (size_t)r * HID_C * HID_C, nullptr, A, N_NODES_C);
        attn_logits_kernel<<<logit_grid, 256, 0, stream>>>(
            A, as2 + r * HID_C, ad2 + r * HID_C, als, ald);
        hipMemsetAsync(den, 0, (size_t)N_NODES_C * HEADS_C * sizeof(float), stream);
        const int* eir = ei + (size_t)r * 2 * N_EDGES_C;
        edge_softmax_kernel<<<esm_grid, 256, 0, stream>>>(eir, als, ald, exb, den);
        edge_aggregate_kernel<<<eagg_grid, 256, 0, stream>>>(eir, A, exb, den, B);
    }
    softsign_ln_kernel<<<ln_grid, 256, 0, stream>>>(B, g2, be2, Cb);

    // ---- pooling + projection ----
    pool_kernel<<<N_GRAPHS_C, 64, 0, stream>>>(Cb, batch, q, pooled);
    gemm_nodes<HID_C><<<N_GRAPHS_C / 32, 256, 0, stream>>>(pooled, Wp, bp, out, N_GRAPHS_C);
}

// Round 2
// 2050.581 us; speedup vs baseline: 5.6302x; 5.6302x over previous
//
#include <hip/hip_runtime.h>
#include <hip/hip_bf16.h>

#define N_NODES_C 100000
#define N_EDGES_C 500000
#define N_REL_C 6
#define IN_DIM_C 64
#define HID_C 128
#define HEADS_C 4
#define CPH_C 32
#define N_GRAPHS_C 1024
#define NBLK_SCAN 391   // ceil(100000/256)

// ---------------- bias init: acc[n][c] = sum_r b[r][c] ----------------
__global__ __launch_bounds__(256) void init_acc_kernel(float* __restrict__ acc,
                                                       const float* __restrict__ b) {
    int i = blockIdx.x * 256 + threadIdx.x;
    if (i >= N_NODES_C * HID_C) return;
    int c = i & (HID_C - 1);
    float s = 0.f;
#pragma unroll
    for (int r = 0; r < N_REL_C; r++) s += b[r * HID_C + c];
    acc[i] = s;
}

// ---------------- CSR build ----------------
__global__ __launch_bounds__(256) void hist_kernel(const int* __restrict__ ei,
                                                   int* __restrict__ cnt) {
    int i = blockIdx.x * 256 + threadIdx.x;
    if (i >= N_REL_C * N_EDGES_C) return;
    int r = i / N_EDGES_C;
    int e = i - r * N_EDGES_C;
    int dst = ei[(size_t)r * 2 * N_EDGES_C + N_EDGES_C + e];
    atomicAdd(&cnt[r * N_NODES_C + dst], 1);
}

// exclusive scan within blocks of 256; blocksums[r][b] = block total
__global__ __launch_bounds__(256) void scan1_kernel(const int* __restrict__ cnt,
                                                    int* __restrict__ rowptr,
                                                    int* __restrict__ blocksums) {
    int r = blockIdx.y, b = blockIdx.x, t = threadIdx.x;
    int idx = b * 256 + t;
    int v = (idx < N_NODES_C) ? cnt[r * N_NODES_C + idx] : 0;
    int orig = v;
    int lane = t & 63, w = t >> 6;
#pragma unroll
    for (int off = 1; off < 64; off <<= 1) {
        int n = __shfl_up(v, off);
        if (lane >= off) v += n;
    }
    __shared__ int wt[4];
    if (lane == 63) wt[w] = v;
    __syncthreads();
    int add = 0;
    for (int i = 0; i < w; i++) add += wt[i];
    v += add;
    if (idx < N_NODES_C) rowptr[(size_t)r * (N_NODES_C + 1) + idx] = v - orig;
    if (t == 255) blocksums[r * NBLK_SCAN + b] = v;
}

// scan the 391 block sums per relation (one block of 512 per relation)
__global__ __launch_bounds__(512) void scan2_kernel(int* __restrict__ blocksums) {
    int r = blockIdx.x, t = threadIdx.x;
    int v = (t < NBLK_SCAN) ? blocksums[r * NBLK_SCAN + t] : 0;
    int orig = v;
    int lane = t & 63, w = t >> 6;
#pragma unroll
    for (int off = 1; off < 64; off <<= 1) {
        int n = __shfl_up(v, off);
        if (lane >= off) v += n;
    }
    __shared__ int wt[8];
    if (lane == 63) wt[w] = v;
    __syncthreads();
    int add = 0;
    for (int i = 0; i < w; i++) add += wt[i];
    v += add;
    if (t < NBLK_SCAN) blocksums[r * NBLK_SCAN + t] = v - orig;  // exclusive
}

__global__ __launch_bounds__(256) void scan3_kernel(int* __restrict__ rowptr,
                                                    const int* __restrict__ blocksums,
                                                    int* __restrict__ cursor) {
    int r = blockIdx.y, b = blockIdx.x, t = threadIdx.x;
    int idx = b * 256 + t;
    if (idx < N_NODES_C) {
        int val = rowptr[(size_t)r * (N_NODES_C + 1) + idx] + blocksums[r * NBLK_SCAN + b];
        rowptr[(size_t)r * (N_NODES_C + 1) + idx] = val;
        cursor[r * N_NODES_C + idx] = val;
    }
    if (b == 0 && t == 0) rowptr[(size_t)r * (N_NODES_C + 1) + N_NODES_C] = N_EDGES_C;
}

__global__ __launch_bounds__(256) void scatter_kernel(const int* __restrict__ ei,
                                                      int* __restrict__ cursor,
                                                      int* __restrict__ srcids) {
    int i = blockIdx.x * 256 + threadIdx.x;
    if (i >= N_REL_C * N_EDGES_C) return;
    int r = i / N_EDGES_C;
    int e = i - r * N_EDGES_C;
    int src = ei[(size_t)r * 2 * N_EDGES_C + e];
    int dst = ei[(size_t)r * 2 * N_EDGES_C + N_EDGES_C + e];
    int pos = atomicAdd(&cursor[r * N_NODES_C + dst], 1);
    srcids[(size_t)r * N_EDGES_C + pos] = src;
}

// ---------------- GEMM with fused attention-logit epilogue ----------------
// H[n][c] = sum_k X[n][k]*W[k][c] (+bias). If als != nullptr, also writes
// als[n][h] = sum_c H[n][h*32+c]*a_s[h][c], ald likewise (pre-bias H).
template <int K>
__global__ __launch_bounds__(256) void gemm_nodes(const float* __restrict__ X,
                                                  const float* __restrict__ W,
                                                  const float* __restrict__ bias,
                                                  float* __restrict__ H, int nrows,
                                                  const float* __restrict__ a_s,
                                                  const float* __restrict__ a_d,
                                                  float* __restrict__ als,
                                                  float* __restrict__ ald) {
    __shared__ float Wl[64 * HID_C];   // 32KB
    __shared__ float Xl[32 * K];       // 8KB / 16KB
    const int t = threadIdx.x;
    const int n0 = blockIdx.x * 32;
    const float* Xb = X + (size_t)n0 * K;
    for (int i = t; i < 32 * K / 4; i += 256)
        ((float4*)Xl)[i] = ((const float4*)Xb)[i];

    const int cg = t & 31, rg = t >> 5;
    const int c0 = cg * 4, r0 = rg * 4;
    float acc[4][4];
#pragma unroll
    for (int i = 0; i < 4; i++)
#pragma unroll
        for (int j = 0; j < 4; j++) acc[i][j] = 0.f;

    for (int kb = 0; kb < K; kb += 64) {
        __syncthreads();
        for (int i = t; i < 64 * HID_C / 4; i += 256)
            ((float4*)Wl)[i] = ((const float4*)(W + (size_t)kb * HID_C))[i];
        __syncthreads();
#pragma unroll 4
        for (int k = 0; k < 64; k += 4) {
            float xr[4][4];
#pragma unroll
            for (int i = 0; i < 4; i++) {
                float4 xv = *(const float4*)&Xl[(r0 + i) * K + kb + k];
                xr[i][0] = xv.x; xr[i][1] = xv.y; xr[i][2] = xv.z; xr[i][3] = xv.w;
            }
#pragma unroll
            for (int kk = 0; kk < 4; kk++) {
                float4 wv = *(const float4*)&Wl[(k + kk) * HID_C + c0];
#pragma unroll
                for (int i = 0; i < 4; i++) {
                    acc[i][0] = fmaf(xr[i][kk], wv.x, acc[i][0]);
                    acc[i][1] = fmaf(xr[i][kk], wv.y, acc[i][1]);
                    acc[i][2] = fmaf(xr[i][kk], wv.z, acc[i][2]);
                    acc[i][3] = fmaf(xr[i][kk], wv.w, acc[i][3]);
                }
            }
        }
    }
    float4 bv = make_float4(0.f, 0.f, 0.f, 0.f);
    if (bias) bv = *(const float4*)&bias[c0];
#pragma unroll
    for (int i = 0; i < 4; i++) {
        int row = n0 + r0 + i;
        if (row < nrows) {
            float4 o;
            o.x = acc[i][0] + bv.x; o.y = acc[i][1] + bv.y;
            o.z = acc[i][2] + bv.z; o.w = acc[i][3] + bv.w;
            *(float4*)&H[(size_t)row * HID_C + c0] = o;
        }
    }
    // fused attention-logit epilogue
    if (als != nullptr) {
        const int head = cg >> 3;
        const int coff = c0 & 31;
        float as4[4], ad4[4];
#pragma unroll
        for (int j = 0; j < 4; j++) {
            as4[j] = a_s[head * CPH_C + coff + j];
            ad4[j] = a_d[head * CPH_C + coff + j];
        }
        float ps[4], pd[4];
#pragma unroll
        for (int i = 0; i < 4; i++) {
            float s = 0.f, d = 0.f;
#pragma unroll
            for (int j = 0; j < 4; j++) {
                s = fmaf(acc[i][j], as4[j], s);
                d = fmaf(acc[i][j], ad4[j], d);
            }
            ps[i] = s; pd[i] = d;
        }
#pragma unroll
        for (int off = 1; off < 8; off <<= 1) {
#pragma unroll
            for (int i = 0; i < 4; i++) {
                ps[i] += __shfl_xor(ps[i], off);
                pd[i] += __shfl_xor(pd[i], off);
            }
        }
        if ((t & 7) == 0) {
#pragma unroll
            for (int i = 0; i < 4; i++) {
                int row = n0 + r0 + i;
                if (row < nrows) {
                    als[row * HEADS_C + head] = ps[i];
                    ald[row * HEADS_C + head] = pd[i];
                }
            }
        }
    }
}

// ---------------- fused per-node softmax + aggregate (CSR, no atomics) ----
// one wave per dst node; lane handles channels 2*lane, 2*lane+1 (head=lane>>4)
__global__ __launch_bounds__(256) void csr_aggregate_kernel(
    const int* __restrict__ rowptr, const int* __restrict__ srcids,
    const float* __restrict__ H, const float* __restrict__ als,
    const float* __restrict__ ald, float* __restrict__ B) {
    int node = blockIdx.x * 4 + (threadIdx.x >> 6);
    int lane = threadIdx.x & 63;
    int h0 = lane >> 4;
    float aldv = ald[node * HEADS_C + h0];
    int s = rowptr[node], e = rowptr[node + 1];
    float acc0 = 0.f, acc1 = 0.f, den = 0.f;
    int src = (s < e) ? srcids[s] : 0;
    for (int i = s; i < e; i++) {
        int nsrc = (i + 1 < e) ? srcids[i + 1] : 0;
        float v = als[src * HEADS_C + h0] + aldv;
        v = v > 0.f ? v : 0.2f * v;
        float ex = expf(v);
        float2 hv = *(const float2*)(H + (size_t)src * HID_C + lane * 2);
        den += ex;
        acc0 = fmaf(ex, hv.x, acc0);
        acc1 = fmaf(ex, hv.y, acc1);
        src = nsrc;
    }
    float inv = 1.f / (den + 1e-16f);
    float* bp = B + (size_t)node * HID_C + lane * 2;
    float2 b = *(float2*)bp;
    b.x += acc0 * inv;
    b.y += acc1 * inv;
    *(float2*)bp = b;
}

// ---------------- softsign + layernorm ----------------
__global__ __launch_bounds__(256) void softsign_ln_kernel(const float* __restrict__ in,
                                                          const float* __restrict__ g,
                                                          const float* __restrict__ be,
                                                          float* __restrict__ out) {
    int t = threadIdx.x;
    int n = blockIdx.x * 4 + (t >> 6);
    int lane = t & 63;
    float2 v = *(const float2*)(in + (size_t)n * HID_C + lane * 2);
    float s0 = v.x / (1.f + fabsf(v.x));
    float s1 = v.y / (1.f + fabsf(v.y));
    float sum = s0 + s1, sq = s0 * s0 + s1 * s1;
#pragma unroll
    for (int off = 1; off < 64; off <<= 1) {
        sum += __shfl_xor(sum, off);
        sq += __shfl_xor(sq, off);
    }
    float mu = sum * (1.f / 128.f);
    float var = sq * (1.f / 128.f) - mu * mu;
    float inv = rsqrtf(var + 1e-5f);
    float2 gv = *(const float2*)(g + lane * 2);
    float2 bv = *(const float2*)(be + lane * 2);
    float2 o;
    o.x = (s0 - mu) * inv * gv.x + bv.x;
    o.y = (s1 - mu) * inv * gv.y + bv.y;
    *(float2*)(out + (size_t)n * HID_C + lane * 2) = o;
}

__device__ __forceinline__ int lower_bound_i(const int* __restrict__ a, int n, int v) {
    int lo = 0, hi = n;
    while (lo < hi) {
        int mid = (lo + hi) >> 1;
        if (a[mid] < v) lo = mid + 1; else hi = mid;
    }
    return lo;
}

// one wave (64 threads) per graph; batch is sorted
__global__ void pool_kernel(const float* __restrict__ H, const int* __restrict__ batch,
                            const float* __restrict__ q, float* __restrict__ pooled) {
    int g = blockIdx.x;
    int lane = threadIdx.x;
    int start = lower_bound_i(batch, N_NODES_C, g);
    int end = lower_bound_i(batch, N_NODES_C, g + 1);
    float q0 = q[lane * 2], q1 = q[lane * 2 + 1];
    float p0 = 0.f, p1 = 0.f, den = 0.f;
    for (int n = start; n < end; n++) {
        float2 hv = *(const float2*)(H + (size_t)n * HID_C + lane * 2);
        float part = hv.x * q0 + hv.y * q1;
#pragma unroll
        for (int off = 1; off < 64; off <<= 1) part += __shfl_xor(part, off);
        float exs = expf(part);
        den += exs;
        p0 += exs * hv.x;
        p1 += exs * hv.y;
    }
    float w = 1.f / (den + 1e-16f);
    pooled[(size_t)g * HID_C + lane * 2] = p0 * w;
    pooled[(size_t)g * HID_C + lane * 2 + 1] = p1 * w;
}

extern "C" void kernel_launch(void* const* d_in, const int* in_sizes, int n_in,
                              void* d_out, int out_size, void* d_ws, size_t ws_size,
                              hipStream_t stream) {
    const float* x   = (const float*)d_in[0];
    const int* ei    = (const int*)d_in[1];    // [6,2,E]
    const int* batch = (const int*)d_in[2];
    const float* W1  = (const float*)d_in[3];
    const float* as1 = (const float*)d_in[4];
    const float* ad1 = (const float*)d_in[5];
    const float* b1  = (const float*)d_in[6];
    const float* W2  = (const float*)d_in[7];
    const float* as2 = (const float*)d_in[8];
    const float* ad2 = (const float*)d_in[9];
    const float* b2  = (const float*)d_in[10];
    const float* g1  = (const float*)d_in[11];
    const float* be1 = (const float*)d_in[12];
    const float* g2  = (const float*)d_in[13];
    const float* be2 = (const float*)d_in[14];
    const float* q   = (const float*)d_in[15];
    const float* Wp  = (const float*)d_in[16];
    const float* bp  = (const float*)d_in[17];
    float* out = (float*)d_out;

    float* ws = (float*)d_ws;
    const size_t NH = (size_t)N_NODES_C * HID_C;            // 12.8M floats
    float* A   = ws;                                        // h_r temp [N,128]
    float* B   = ws + NH;                                   // accumulator [N,128]
    float* Cb  = ws + 2 * NH;                               // LN output [N,128]
    float* als = ws + 3 * NH;                               // [N,4]
    float* ald = als + (size_t)N_NODES_C * HEADS_C;
    float* pooled = ald + (size_t)N_NODES_C * HEADS_C;      // [1024,128]
    int* iws = (int*)(pooled + (size_t)N_GRAPHS_C * HID_C);
    int* cnt      = iws;                                    // [6][100000]
    int* rowptr   = cnt + N_REL_C * N_NODES_C;              // [6][100001]
    int* cursor   = rowptr + N_REL_C * (N_NODES_C + 1);     // [6][100000]
    int* blocksums= cursor + N_REL_C * N_NODES_C;           // [6][391]
    int* srcids   = blocksums + N_REL_C * NBLK_SCAN;        // [6][500000]

    const int gemm_grid_n = N_NODES_C / 32;                 // 3125
    const int agg_grid = N_NODES_C / 4;                     // 25000
    const int ln_grid = N_NODES_C / 4;

    // ---- build CSR (topology shared by both layers) ----
    hipMemsetAsync(cnt, 0, (size_t)N_REL_C * N_NODES_C * sizeof(int), stream);
    const int ehg = (N_REL_C * N_EDGES_C + 255) / 256;
    hist_kernel<<<ehg, 256, 0, stream>>>(ei, cnt);
    scan1_kernel<<<dim3(NBLK_SCAN, N_REL_C), 256, 0, stream>>>(cnt, rowptr, blocksums);
    scan2_kernel<<<N_REL_C, 512, 0, stream>>>(blocksums);
    scan3_kernel<<<dim3(NBLK_SCAN, N_REL_C), 256, 0, stream>>>(rowptr, blocksums, cursor);
    scatter_kernel<<<ehg, 256, 0, stream>>>(ei, cursor, srcids);

    // ---- layer 1 ----
    init_acc_kernel<<<N_NODES_C * HID_C / 256, 256, 0, stream>>>(B, b1);
    for (int r = 0; r < N_REL_C; r++) {
        gemm_nodes<IN_DIM_C><<<gemm_grid_n, 256, 0, stream>>>(
            x, W1 + (size_t)r * IN_DIM_C * HID_C, nullptr, A, N_NODES_C,
            as1 + r * HID_C, ad1 + r * HID_C, als, ald);
        csr_aggregate_kernel<<<agg_grid, 256, 0, stream>>>(
            rowptr + (size_t)r * (N_NODES_C + 1), srcids + (size_t)r * N_EDGES_C,
            A, als, ald, B);
    }
    softsign_ln_kernel<<<ln_grid, 256, 0, stream>>>(B, g1, be1, Cb);

    // ---- layer 2 ----
    init_acc_kernel<<<N_NODES_C * HID_C / 256, 256, 0, stream>>>(B, b2);
    for (int r = 0; r < N_REL_C; r++) {
        gemm_nodes<HID_C><<<gemm_grid_n, 256, 0, stream>>>(
            Cb, W2 + (size_t)r * HID_C * HID_C, nullptr, A, N_NODES_C,
            as2 + r * HID_C, ad2 + r * HID_C, als, ald);
        csr_aggregate_kernel<<<agg_grid, 256, 0, stream>>>(
            rowptr + (size_t)r * (N_NODES_C + 1), srcids + (size_t)r * N_EDGES_C,
            A, als, ald, B);
    }
    softsign_ln_kernel<<<ln_grid, 256, 0, stream>>>(B, g2, be2, Cb);

    // ---- pooling + projection ----
    pool_kernel<<<N_GRAPHS_C, 64, 0, stream>>>(Cb, batch, q, pooled);
    gemm_nodes<HID_C><<<N_GRAPHS_C / 32, 256, 0, stream>>>(
        pooled, Wp, bp, out, N_GRAPHS_C, nullptr, nullptr, nullptr, nullptr);
}